// Round 1
// baseline (99.660 us; speedup 1.0000x reference)
//
#include <hip/hip_runtime.h>
#include <math.h>

// 6-qubit statevector sim, one batch element per LANE PAIR (2 threads/element).
// Qubit q occupies bit (5-q) of the global amplitude index (q0 = MSB, matches
// the reference's C-contiguous flatten). q0's bit (mask 32) is the lane
// parity: lane (2b+p) holds the 32 amplitudes of element b with bit5 == p.
// Cross-thread ops (gate on q0, CNOTs touching q0) use DPP quad_perm lane^1
// exchanges: 1 VALU instr per float, no LDS round-trip.
// Rationale: 32 amps = 64 VGPRs of state -> <=128 VGPR -> 4 waves/SIMD
// (vs 2 before); rolled layer loop keeps code ~14 KB (I-cache is 32 KB).

struct cf { float r, i; };

__device__ __forceinline__ cf cmul(cf a, cf b) {
    return { fmaf(a.r, b.r, -a.i * b.i), fmaf(a.r, b.i, a.i * b.r) };
}
// acc + g*v
__device__ __forceinline__ cf cmac(cf acc, cf g, cf v) {
    acc.r = fmaf(g.r, v.r, fmaf(-g.i, v.i, acc.r));
    acc.i = fmaf(g.r, v.i, fmaf(g.i, v.r, acc.i));
    return acc;
}

// lane ^ 1 exchange via DPP quad_perm [1,0,3,2] — single VALU instruction.
__device__ __forceinline__ float xpair(float v) {
    return __int_as_float(__builtin_amdgcn_mov_dpp(__float_as_int(v), 0xB1, 0xF, 0xF, true));
}
__device__ __forceinline__ cf xpair(cf v) { return { xpair(v.r), xpair(v.i) }; }

// Apply 2x2 complex gate to a LOCAL qubit with mask M (compile-time), 32 amps.
template<int M>
__device__ __forceinline__ void apply1q(cf* st, cf g00, cf g01, cf g10, cf g11) {
#pragma unroll
    for (int j = 0; j < 32; ++j) {
        if (j & M) continue;
        cf a = st[j], b = st[j + M];
        cf na = cmul(g00, a); na = cmac(na, g01, b);
        cf nb = cmul(g10, a); nb = cmac(nb, g11, b);
        st[j] = na; st[j + M] = nb;
    }
}

// Local CNOT: pure register renaming after unroll.
template<int MC, int MT>
__device__ __forceinline__ void cnot(cf* st) {
#pragma unroll
    for (int j = 0; j < 32; ++j) {
        if ((j & MC) && !(j & MT)) {
            cf tmp = st[j]; st[j] = st[j + MT]; st[j + MT] = tmp;
        }
    }
}

__global__ __launch_bounds__(256, 4) void qsim_kernel(
    const float* __restrict__ x, const float* __restrict__ theta,
    float* __restrict__ out) {
    // ---- per-block: build the 18 fused RZ*RY*RX gate matrices into LDS ----
    __shared__ float gs[18 * 8];
    const int t = threadIdx.x;
    if (t < 18) {
        const float* th = theta + t * 3;   // theta[l][q][0..2], t = l*6+q
        float sx, cx, sy, cy, sz, cz;
        __sincosf(0.5f * th[0], &sx, &cx);
        __sincosf(0.5f * th[1], &sy, &cy);
        __sincosf(0.5f * th[2], &sz, &cz);
        // M = RY * RX
        cf m00 = {  cy * cx,  sy * sx };
        cf m01 = { -sy * cx, -cy * sx };
        cf m10 = {  sy * cx, -cy * sx };
        cf m11 = {  cy * cx, -sy * sx };
        // G = RZ * M : row0 *= e^{-i th2/2}, row1 *= e^{+i th2/2}
        cf e0 = { cz, -sz }, e1 = { cz, sz };
        cf g00 = cmul(e0, m00), g01 = cmul(e0, m01);
        cf g10 = cmul(e1, m10), g11 = cmul(e1, m11);
        float* o = gs + t * 8;
        o[0] = g00.r; o[1] = g00.i; o[2] = g01.r; o[3] = g01.i;
        o[4] = g10.r; o[5] = g10.i; o[6] = g11.r; o[7] = g11.i;
    }
    __syncthreads();

    const int tg = blockIdx.x * 256 + t;
    const int b  = tg >> 1;            // batch element
    const bool pb = (tg & 1) != 0;     // this lane's value of global bit5 (q0)

    // ---- encoding: angles from x, then tensor-product initial half-state ----
    const float4* xv = reinterpret_cast<const float4*>(x + (size_t)b * 24);
    float4 xq[6];
#pragma unroll
    for (int q = 0; q < 6; ++q) xq[q] = xv[q];

    cf st[32];
#pragma unroll
    for (int q = 0; q < 6; ++q) {
        float4 v = xq[q];
        float m = (v.x + v.y + v.z + v.w) * 0.25f;
        m = fminf(fmaxf(m, -6.0f), 6.0f);
        float a = m * 0.52359877559829887308f;   // pi/6
        float s2, c2, s4, c4;
        __sincosf(0.50f * a, &s2, &c2);
        __sincosf(0.25f * a, &s4, &c4);
        // column of RZ(a/2)*RX(a) applied to |0>
        cf v0 = { c4 * c2, -s4 * c2 };
        cf v1 = { s4 * s2, -c4 * s2 };
        if (q == 0) {
            st[0] = pb ? v1 : v0;               // q0 component = lane parity
        } else {
            const int mq = 32 >> q;             // local masks 16,8,4,2,1
#pragma unroll
            for (int i = 0; i < 32; i += 2 * mq) {
                st[i + mq] = cmul(st[i], v1);   // write high half first
                st[i]      = cmul(st[i], v0);
            }
        }
    }

    // ---- 3 layers: CNOT ring + fused 1q gates (rolled loop: I-cache) ----
#pragma unroll 1
    for (int l = 0; l < 3; ++l) {
        // CNOT(0,1): control = bit5 = lane parity; p==1 swaps local j <-> j+16
#pragma unroll
        for (int j = 0; j < 16; ++j) {
            cf lo = st[j], hi = st[j + 16];
            st[j]      = pb ? hi : lo;
            st[j + 16] = pb ? lo : hi;
        }
        cnot<16, 8>(st);   // CNOT(1,2)
        cnot< 8, 4>(st);   // CNOT(2,3)
        cnot< 4, 2>(st);   // CNOT(3,4)
        cnot< 2, 1>(st);   // CNOT(4,5)
        // CNOT(5,0): control = local bit0, target = bit5: cross-lane swap, odd j
#pragma unroll
        for (int j = 1; j < 32; j += 2) st[j] = xpair(st[j]);

        const float* g = gs + l * 48;

        // gate on q0 (split across the lane pair):
        // thread p=0: st[j] = g00*mine + g01*other
        // thread p=1: st[j] = g11*mine + g10*other
        {
            cf q00 = { g[0], g[1] }, q01 = { g[2], g[3] };
            cf q10 = { g[4], g[5] }, q11 = { g[6], g[7] };
            cf gm = pb ? q11 : q00;   // coefficient of my amplitude
            cf go = pb ? q10 : q01;   // coefficient of partner amplitude
#pragma unroll
            for (int j = 0; j < 32; ++j) {
                cf other = xpair(st[j]);          // lockstep: both lanes read pre-update
                cf nv = cmul(gm, st[j]);
                st[j] = cmac(nv, go, other);
            }
        }
        // local gates q1..q5
#define G4(o) cf{g[(o)+0], g[(o)+1]}, cf{g[(o)+2], g[(o)+3]}, \
              cf{g[(o)+4], g[(o)+5]}, cf{g[(o)+6], g[(o)+7]}
        apply1q<16>(st, G4(8));
        apply1q< 8>(st, G4(16));
        apply1q< 4>(st, G4(24));
        apply1q< 2>(st, G4(32));
        apply1q< 1>(st, G4(40));
#undef G4
    }

    // ---- measurements ----
    // local bit map: bit4=q1, bit3=q2, bit2=q3, bit1=q4, bit0=q5
    // Z0 sign = lane parity; Z2 sign = local bit3; Z4 sign = local bit1
    float s[4] = { 0, 0, 0, 0 };
#pragma unroll
    for (int j = 0; j < 32; ++j) {
        float pj = fmaf(st[j].r, st[j].r, st[j].i * st[j].i);
        const int gi = (((j >> 3) & 1) << 1) | ((j >> 1) & 1);
        s[gi] += pj;
    }
    float tot = (s[0] + s[1]) + (s[2] + s[3]);
    float z0 = pb ? -tot : tot;
    float z2 = (s[0] + s[1]) - (s[2] + s[3]);
    float z4 = (s[0] + s[2]) - (s[1] + s[3]);

    float x1 = 0.f, x3 = 0.f, x5 = 0.f;   // X1/X3/X5 pair up within a lane
#pragma unroll
    for (int j = 0; j < 32; ++j) {
        if (!(j & 16)) x1 = fmaf(st[j].r, st[j + 16].r, fmaf(st[j].i, st[j + 16].i, x1));
        if (!(j &  4)) x3 = fmaf(st[j].r, st[j +  4].r, fmaf(st[j].i, st[j +  4].i, x3));
        if (!(j &  1)) x5 = fmaf(st[j].r, st[j +  1].r, fmaf(st[j].i, st[j +  1].i, x5));
    }

    // combine the two half-state partials of each element
    z0 += xpair(z0); z2 += xpair(z2); z4 += xpair(z4);
    x1 += xpair(x1); x3 += xpair(x3); x5 += xpair(x5);
    x1 *= 2.f; x3 *= 2.f; x5 *= 2.f;

    // out[b] = {z0, x1, z2, x3, z4, x5, z0, x1}; lane p writes float4 #p
    float oa = pb ? z4 : z0;
    float ob = pb ? x5 : x1;
    float oc = pb ? z0 : z2;
    float od = pb ? x1 : x3;
    float4* ov = reinterpret_cast<float4*>(out + (size_t)b * 8);
    ov[pb ? 1 : 0] = make_float4(oa, ob, oc, od);
}

extern "C" void kernel_launch(void* const* d_in, const int* in_sizes, int n_in,
                              void* d_out, int out_size, void* d_ws, size_t ws_size,
                              hipStream_t stream) {
    const float* x     = (const float*)d_in[0];   // [B, 24] f32
    const float* theta = (const float*)d_in[1];   // [3, 6, 3] f32
    float* out = (float*)d_out;                   // [B, 8] f32
    const int B = in_sizes[0] / 24;               // 131072
    qsim_kernel<<<dim3((B * 2) / 256), dim3(256), 0, stream>>>(x, theta, out);
}

// Round 2
// 86.790 us; speedup vs baseline: 1.1483x; 1.1483x over previous
//
#include <hip/hip_runtime.h>
#include <math.h>

// 6-qubit statevector sim, one batch element per LANE PAIR (2 threads/element).
// Qubit q occupies bit (5-q) of the global amplitude index (q0 = MSB, matches
// the reference's C-contiguous flatten). q0's bit (mask 32) is the lane
// parity: lane (2b+p) holds the 32 amplitudes of element b with bit5 == p.
// Cross-thread ops (gate on q0, CNOTs touching q0) use DPP quad_perm lane^1
// exchanges: 1 VALU instr per float, no LDS round-trip.
//
// launch_bounds NOTE (round-1 post-mortem): (256, 4) made the backend cap the
// kernel at 64 VGPRs (empirically budget = 256/waves_per_eu, not 512/) ->
// the 64-float state spilled to scratch: WRITE_SIZE 76 MB vs 4 MB output,
// kernel 48 us. (256, 2) gives a >=128-VGPR budget under either accounting;
// peak live pressure is ~110 floats, so no spill, and <=128 VGPRs still
// allows 4 waves/SIMD occupancy.

struct cf { float r, i; };

__device__ __forceinline__ cf cmul(cf a, cf b) {
    return { fmaf(a.r, b.r, -a.i * b.i), fmaf(a.r, b.i, a.i * b.r) };
}
// acc + g*v
__device__ __forceinline__ cf cmac(cf acc, cf g, cf v) {
    acc.r = fmaf(g.r, v.r, fmaf(-g.i, v.i, acc.r));
    acc.i = fmaf(g.r, v.i, fmaf(g.i, v.r, acc.i));
    return acc;
}

// lane ^ 1 exchange via DPP quad_perm [1,0,3,2] — single VALU instruction.
__device__ __forceinline__ float xpair(float v) {
    return __int_as_float(__builtin_amdgcn_mov_dpp(__float_as_int(v), 0xB1, 0xF, 0xF, true));
}
__device__ __forceinline__ cf xpair(cf v) { return { xpair(v.r), xpair(v.i) }; }

// Apply 2x2 complex gate to a LOCAL qubit with mask M (compile-time), 32 amps.
template<int M>
__device__ __forceinline__ void apply1q(cf* st, cf g00, cf g01, cf g10, cf g11) {
#pragma unroll
    for (int j = 0; j < 32; ++j) {
        if (j & M) continue;
        cf a = st[j], b = st[j + M];
        cf na = cmul(g00, a); na = cmac(na, g01, b);
        cf nb = cmul(g10, a); nb = cmac(nb, g11, b);
        st[j] = na; st[j + M] = nb;
    }
}

// Local CNOT: pure register renaming after unroll.
template<int MC, int MT>
__device__ __forceinline__ void cnot(cf* st) {
#pragma unroll
    for (int j = 0; j < 32; ++j) {
        if ((j & MC) && !(j & MT)) {
            cf tmp = st[j]; st[j] = st[j + MT]; st[j + MT] = tmp;
        }
    }
}

__global__ __launch_bounds__(256, 2) void qsim_kernel(
    const float* __restrict__ x, const float* __restrict__ theta,
    float* __restrict__ out) {
    // ---- per-block: build the 18 fused RZ*RY*RX gate matrices into LDS ----
    __shared__ float gs[18 * 8];
    const int t = threadIdx.x;
    if (t < 18) {
        const float* th = theta + t * 3;   // theta[l][q][0..2], t = l*6+q
        float sx, cx, sy, cy, sz, cz;
        __sincosf(0.5f * th[0], &sx, &cx);
        __sincosf(0.5f * th[1], &sy, &cy);
        __sincosf(0.5f * th[2], &sz, &cz);
        // M = RY * RX
        cf m00 = {  cy * cx,  sy * sx };
        cf m01 = { -sy * cx, -cy * sx };
        cf m10 = {  sy * cx, -cy * sx };
        cf m11 = {  cy * cx, -sy * sx };
        // G = RZ * M : row0 *= e^{-i th2/2}, row1 *= e^{+i th2/2}
        cf e0 = { cz, -sz }, e1 = { cz, sz };
        cf g00 = cmul(e0, m00), g01 = cmul(e0, m01);
        cf g10 = cmul(e1, m10), g11 = cmul(e1, m11);
        float* o = gs + t * 8;
        o[0] = g00.r; o[1] = g00.i; o[2] = g01.r; o[3] = g01.i;
        o[4] = g10.r; o[5] = g10.i; o[6] = g11.r; o[7] = g11.i;
    }
    __syncthreads();

    const int tg = blockIdx.x * 256 + t;
    const int b  = tg >> 1;            // batch element
    const bool pb = (tg & 1) != 0;     // this lane's value of global bit5 (q0)

    // ---- encoding: angles from x, then tensor-product initial half-state ----
    const float4* xv = reinterpret_cast<const float4*>(x + (size_t)b * 24);

    cf st[32];
#pragma unroll
    for (int q = 0; q < 6; ++q) {
        float4 v = xv[q];
        float m = (v.x + v.y + v.z + v.w) * 0.25f;
        m = fminf(fmaxf(m, -6.0f), 6.0f);
        float a = m * 0.52359877559829887308f;   // pi/6
        float s2, c2, s4, c4;
        __sincosf(0.50f * a, &s2, &c2);
        __sincosf(0.25f * a, &s4, &c4);
        // column of RZ(a/2)*RX(a) applied to |0>
        cf v0 = { c4 * c2, -s4 * c2 };
        cf v1 = { s4 * s2, -c4 * s2 };
        if (q == 0) {
            st[0] = pb ? v1 : v0;               // q0 component = lane parity
        } else {
            const int mq = 32 >> q;             // local masks 16,8,4,2,1
#pragma unroll
            for (int i = 0; i < 32; i += 2 * mq) {
                st[i + mq] = cmul(st[i], v1);   // write high half first
                st[i]      = cmul(st[i], v0);
            }
        }
    }

    // ---- 3 layers: CNOT ring + fused 1q gates (rolled loop: I-cache) ----
#pragma unroll 1
    for (int l = 0; l < 3; ++l) {
        // CNOT(0,1): control = bit5 = lane parity; p==1 swaps local j <-> j+16
#pragma unroll
        for (int j = 0; j < 16; ++j) {
            cf lo = st[j], hi = st[j + 16];
            st[j]      = pb ? hi : lo;
            st[j + 16] = pb ? lo : hi;
        }
        cnot<16, 8>(st);   // CNOT(1,2)
        cnot< 8, 4>(st);   // CNOT(2,3)
        cnot< 4, 2>(st);   // CNOT(3,4)
        cnot< 2, 1>(st);   // CNOT(4,5)
        // CNOT(5,0): control = local bit0, target = bit5: cross-lane swap, odd j
#pragma unroll
        for (int j = 1; j < 32; j += 2) st[j] = xpair(st[j]);

        const float* g = gs + l * 48;

        // gate on q0 (split across the lane pair):
        // thread p=0: st[j] = g00*mine + g01*other
        // thread p=1: st[j] = g11*mine + g10*other
        {
            cf q00 = { g[0], g[1] }, q01 = { g[2], g[3] };
            cf q10 = { g[4], g[5] }, q11 = { g[6], g[7] };
            cf gm = pb ? q11 : q00;   // coefficient of my amplitude
            cf go = pb ? q10 : q01;   // coefficient of partner amplitude
#pragma unroll
            for (int j = 0; j < 32; ++j) {
                cf other = xpair(st[j]);          // lockstep: both lanes read pre-update
                cf nv = cmul(gm, st[j]);
                st[j] = cmac(nv, go, other);
            }
        }
        // local gates q1..q5
#define G4(o) cf{g[(o)+0], g[(o)+1]}, cf{g[(o)+2], g[(o)+3]}, \
              cf{g[(o)+4], g[(o)+5]}, cf{g[(o)+6], g[(o)+7]}
        apply1q<16>(st, G4(8));
        apply1q< 8>(st, G4(16));
        apply1q< 4>(st, G4(24));
        apply1q< 2>(st, G4(32));
        apply1q< 1>(st, G4(40));
#undef G4
    }

    // ---- measurements ----
    // local bit map: bit4=q1, bit3=q2, bit2=q3, bit1=q4, bit0=q5
    // Z0 sign = lane parity; Z2 sign = local bit3; Z4 sign = local bit1
    float s[4] = { 0, 0, 0, 0 };
#pragma unroll
    for (int j = 0; j < 32; ++j) {
        float pj = fmaf(st[j].r, st[j].r, st[j].i * st[j].i);
        const int gi = (((j >> 3) & 1) << 1) | ((j >> 1) & 1);
        s[gi] += pj;
    }
    float tot = (s[0] + s[1]) + (s[2] + s[3]);
    float z0 = pb ? -tot : tot;
    float z2 = (s[0] + s[1]) - (s[2] + s[3]);
    float z4 = (s[0] + s[2]) - (s[1] + s[3]);

    float x1 = 0.f, x3 = 0.f, x5 = 0.f;   // X1/X3/X5 pair up within a lane
#pragma unroll
    for (int j = 0; j < 32; ++j) {
        if (!(j & 16)) x1 = fmaf(st[j].r, st[j + 16].r, fmaf(st[j].i, st[j + 16].i, x1));
        if (!(j &  4)) x3 = fmaf(st[j].r, st[j +  4].r, fmaf(st[j].i, st[j +  4].i, x3));
        if (!(j &  1)) x5 = fmaf(st[j].r, st[j +  1].r, fmaf(st[j].i, st[j +  1].i, x5));
    }

    // combine the two half-state partials of each element
    z0 += xpair(z0); z2 += xpair(z2); z4 += xpair(z4);
    x1 += xpair(x1); x3 += xpair(x3); x5 += xpair(x5);
    x1 *= 2.f; x3 *= 2.f; x5 *= 2.f;

    // out[b] = {z0, x1, z2, x3, z4, x5, z0, x1}; lane p writes float4 #p
    float oa = pb ? z4 : z0;
    float ob = pb ? x5 : x1;
    float oc = pb ? z0 : z2;
    float od = pb ? x1 : x3;
    float4* ov = reinterpret_cast<float4*>(out + (size_t)b * 8);
    ov[pb ? 1 : 0] = make_float4(oa, ob, oc, od);
}

extern "C" void kernel_launch(void* const* d_in, const int* in_sizes, int n_in,
                              void* d_out, int out_size, void* d_ws, size_t ws_size,
                              hipStream_t stream) {
    const float* x     = (const float*)d_in[0];   // [B, 24] f32
    const float* theta = (const float*)d_in[1];   // [3, 6, 3] f32
    float* out = (float*)d_out;                   // [B, 8] f32
    const int B = in_sizes[0] / 24;               // 131072
    qsim_kernel<<<dim3((B * 2) / 256), dim3(256), 0, stream>>>(x, theta, out);
}

// Round 3
// 83.454 us; speedup vs baseline: 1.1942x; 1.0400x over previous
//
#include <hip/hip_runtime.h>
#include <math.h>

// 6-qubit statevector sim, one batch element per thread, 64 complex amps held
// as float2 (packed re,im) in registers. Qubit q = bit (5-q) of the amp index
// (q0 = MSB, matches the reference's C-contiguous flatten).
//
// Round-2 post-mortem: kernel is pinned at ~0.2 instr/cyc/SIMD regardless of
// occupancy (2 vs 4 waves/SIMD) or spill traffic -> the lever is INSTRUCTION
// COUNT. This version: (a) back to 1 elem/thread so all CNOTs are free
// register renames and no cross-lane ops exist; (b) all complex arithmetic as
// VOP3P packed fp32 (v_pk_fma_f32 with op_sel/neg_lo): complex MAC = 2 instr
// instead of 4 -> gate cost/element 9216 -> 4608 instr; (c) layer loop rolled
// so static code ~18 KB fits the 32 KB I-cache (round-0's 80 KB body did not).
// __launch_bounds__(256) with NO second arg: round-1 showed arg2=N caps VGPR
// at 256/N (=64 for N=4 -> catastrophic spill). Expect ~180-220 VGPR,
// 2 waves/SIMD, WRITE_SIZE == output only (4 MB).

// ---- packed complex primitives -------------------------------------------
// g=(gr,gi), a=(ar,ai) as float2 in a VGPR pair.
// cmul: t = (gr*ar - gi*ai, gr*ai + gi*ar)
__device__ __forceinline__ float2 pk_cmul(float2 g, float2 a) {
    float2 t;
    // t = (gr*ar, gr*ai)   : src0 low half broadcast
    asm("v_pk_mul_f32 %0, %1, %2 op_sel:[0,0] op_sel_hi:[0,1]"
        : "=v"(t) : "v"(g), "v"(a));
    // t += (-gi*ai, gi*ar) : src0 high broadcast, src1 swapped, low negated
    asm("v_pk_fma_f32 %0, %1, %2, %0 op_sel:[1,1,0] op_sel_hi:[1,0,1] neg_lo:[1,0,0]"
        : "+v"(t) : "v"(g), "v"(a));
    return t;
}
// cmac: acc += g*a
__device__ __forceinline__ float2 pk_cmac(float2 acc, float2 g, float2 a) {
    asm("v_pk_fma_f32 %0, %1, %2, %0 op_sel:[0,0,0] op_sel_hi:[0,1,1]"
        : "+v"(acc) : "v"(g), "v"(a));
    asm("v_pk_fma_f32 %0, %1, %2, %0 op_sel:[1,1,0] op_sel_hi:[1,0,1] neg_lo:[1,0,0]"
        : "+v"(acc) : "v"(g), "v"(a));
    return acc;
}
// acc += a*a  (elementwise: (r^2, i^2)) — for probability sums
__device__ __forceinline__ float2 pk_sqacc(float2 acc, float2 a) {
    asm("v_pk_fma_f32 %0, %1, %1, %0" : "+v"(acc) : "v"(a));
    return acc;
}
// acc += a*b  (elementwise) — for Re<psi|X|psi> pair sums
__device__ __forceinline__ float2 pk_macv(float2 acc, float2 a, float2 b) {
    asm("v_pk_fma_f32 %0, %1, %2, %0" : "+v"(acc) : "v"(a), "v"(b));
    return acc;
}

// Apply 2x2 complex gate to qubit with mask M (compile-time).
template<int M>
__device__ __forceinline__ void apply1q(float2* st, float2 g00, float2 g01,
                                        float2 g10, float2 g11) {
#pragma unroll
    for (int i = 0; i < 64; ++i) {
        if (i & M) continue;
        float2 a = st[i], b = st[i + M];
        float2 na = pk_cmul(g00, a); na = pk_cmac(na, g01, b);
        float2 nb = pk_cmul(g10, a); nb = pk_cmac(nb, g11, b);
        st[i] = na; st[i + M] = nb;
    }
}

// CNOT control-mask MC, target-mask MT: pure register renaming after unroll.
template<int MC, int MT>
__device__ __forceinline__ void cnot(float2* st) {
#pragma unroll
    for (int i = 0; i < 64; ++i) {
        if ((i & MC) && !(i & MT)) {
            float2 tmp = st[i]; st[i] = st[i + MT]; st[i + MT] = tmp;
        }
    }
}

struct cf { float r, i; };
__device__ __forceinline__ cf scmul(cf a, cf b) {
    return { fmaf(a.r, b.r, -a.i * b.i), fmaf(a.r, b.i, a.i * b.r) };
}

__global__ __launch_bounds__(256) void qsim_kernel(
    const float* __restrict__ x, const float* __restrict__ theta,
    float* __restrict__ out) {
    // ---- per-block: build the 18 fused RZ*RY*RX gate matrices into LDS ----
    __shared__ float2 gs[18 * 4];
    const int t = threadIdx.x;
    if (t < 18) {
        const float* th = theta + t * 3;   // theta[l][q][0..2], t = l*6+q
        float sx, cx, sy, cy, sz, cz;
        __sincosf(0.5f * th[0], &sx, &cx);
        __sincosf(0.5f * th[1], &sy, &cy);
        __sincosf(0.5f * th[2], &sz, &cz);
        // M = RY * RX
        cf m00 = {  cy * cx,  sy * sx };
        cf m01 = { -sy * cx, -cy * sx };
        cf m10 = {  sy * cx, -cy * sx };
        cf m11 = {  cy * cx, -sy * sx };
        // G = RZ * M : row0 *= e^{-i th2/2}, row1 *= e^{+i th2/2}
        cf e0 = { cz, -sz }, e1 = { cz, sz };
        cf g00 = scmul(e0, m00), g01 = scmul(e0, m01);
        cf g10 = scmul(e1, m10), g11 = scmul(e1, m11);
        float2* o = gs + t * 4;
        o[0] = make_float2(g00.r, g00.i);
        o[1] = make_float2(g01.r, g01.i);
        o[2] = make_float2(g10.r, g10.i);
        o[3] = make_float2(g11.r, g11.i);
    }
    __syncthreads();

    const int b = blockIdx.x * 256 + t;

    // ---- encoding: angles from x, then tensor-product initial state ----
    const float4* xv = reinterpret_cast<const float4*>(x + (size_t)b * 24);
    float2 v0[6], v1[6];
#pragma unroll
    for (int q = 0; q < 6; ++q) {
        float4 xq = xv[q];
        float m = (xq.x + xq.y + xq.z + xq.w) * 0.25f;
        m = fminf(fmaxf(m, -6.0f), 6.0f);
        float a = m * 0.52359877559829887308f;   // pi/6
        float s2, c2, s4, c4;
        __sincosf(0.50f * a, &s2, &c2);
        __sincosf(0.25f * a, &s4, &c4);
        // column of RZ(a/2)*RX(a) applied to |0>
        v0[q] = make_float2(c4 * c2, -s4 * c2);
        v1[q] = make_float2(s4 * s2, -c4 * s2);
    }

    float2 st[64];
    st[0] = v0[0]; st[32] = v1[0];
#pragma unroll
    for (int q = 1; q < 6; ++q) {
        const int m = 32 >> q;
#pragma unroll
        for (int i = 0; i < 64; i += 2 * m) {
            st[i + m] = pk_cmul(st[i], v1[q]);   // write high half first
            st[i]     = pk_cmul(st[i], v0[q]);
        }
    }

    // ---- 3 layers: CNOT ring + fused 1q gates (rolled: I-cache) ----
#pragma unroll 1
    for (int l = 0; l < 3; ++l) {
        cnot<32, 16>(st);   // CNOT(0,1)
        cnot<16,  8>(st);   // CNOT(1,2)
        cnot< 8,  4>(st);   // CNOT(2,3)
        cnot< 4,  2>(st);   // CNOT(3,4)
        cnot< 2,  1>(st);   // CNOT(4,5)
        cnot< 1, 32>(st);   // CNOT(5,0)
        const float2* g = gs + l * 24;
        apply1q<32>(st, g[ 0], g[ 1], g[ 2], g[ 3]);
        apply1q<16>(st, g[ 4], g[ 5], g[ 6], g[ 7]);
        apply1q< 8>(st, g[ 8], g[ 9], g[10], g[11]);
        apply1q< 4>(st, g[12], g[13], g[14], g[15]);
        apply1q< 2>(st, g[16], g[17], g[18], g[19]);
        apply1q< 1>(st, g[20], g[21], g[22], g[23]);
    }

    // ---- measurements: Z0,Z2,Z4 via 8 sign-buckets; X1,X3,X5 via pair sums ----
    float2 ps[8];
#pragma unroll
    for (int k = 0; k < 8; ++k) ps[k] = make_float2(0.f, 0.f);
#pragma unroll
    for (int i = 0; i < 64; ++i) {
        const int gi = (((i >> 5) & 1) << 2) | (((i >> 3) & 1) << 1) | ((i >> 1) & 1);
        ps[gi] = pk_sqacc(ps[gi], st[i]);
    }
    float s[8];
#pragma unroll
    for (int k = 0; k < 8; ++k) s[k] = ps[k].x + ps[k].y;
    float z0 = (s[0] + s[1] + s[2] + s[3]) - (s[4] + s[5] + s[6] + s[7]);
    float z2 = (s[0] + s[1] + s[4] + s[5]) - (s[2] + s[3] + s[6] + s[7]);
    float z4 = (s[0] + s[2] + s[4] + s[6]) - (s[1] + s[3] + s[5] + s[7]);

    float2 xa = make_float2(0.f, 0.f), xb = xa, xc = xa;
#pragma unroll
    for (int i = 0; i < 64; ++i) {
        if (!(i & 16)) xa = pk_macv(xa, st[i], st[i + 16]);
        if (!(i &  4)) xb = pk_macv(xb, st[i], st[i +  4]);
        if (!(i &  1)) xc = pk_macv(xc, st[i], st[i +  1]);
    }
    float x1 = 2.f * (xa.x + xa.y);
    float x3 = 2.f * (xb.x + xb.y);
    float x5 = 2.f * (xc.x + xc.y);

    float4* ov = reinterpret_cast<float4*>(out + (size_t)b * 8);
    ov[0] = make_float4(z0, x1, z2, x3);
    ov[1] = make_float4(z4, x5, z0, x1);   // k=6 dups Z0, k=7 dups X1
}

extern "C" void kernel_launch(void* const* d_in, const int* in_sizes, int n_in,
                              void* d_out, int out_size, void* d_ws, size_t ws_size,
                              hipStream_t stream) {
    const float* x     = (const float*)d_in[0];   // [B, 24] f32
    const float* theta = (const float*)d_in[1];   // [3, 6, 3] f32
    float* out = (float*)d_out;                   // [B, 8] f32
    const int B = in_sizes[0] / 24;               // 131072
    qsim_kernel<<<dim3(B / 256), dim3(256), 0, stream>>>(x, theta, out);
}